// Round 15
// baseline (2243.216 us; speedup 1.0000x reference)
//
#include <hip/hip_runtime.h>
#include <hip/hip_bf16.h>

#define SEQ   2048
#define DH    64
#define NBH   64          // B*H
#define NH    16
#define QT    16          // q-rows per block
#define NW    8           // waves per block
#define NT    (NW * 64)
#define CHUNK 128         // k-cols staged per iteration
#define NCH   (SEQ / CHUNK)

typedef __attribute__((ext_vector_type(8))) short short8;
typedef __attribute__((ext_vector_type(4))) short short4v;
typedef __attribute__((ext_vector_type(4))) float f32x4;
typedef __attribute__((ext_vector_type(4))) int   i32x4;
typedef __attribute__((ext_vector_type(4))) unsigned short u16x4;

__device__ __forceinline__ unsigned short f2bf(float x) {
    union { float f; unsigned u; } c; c.f = x;
    return (unsigned short)((c.u + 0x7fffu + ((c.u >> 16) & 1u)) >> 16);
}
__device__ __forceinline__ unsigned pk2(float a, float b) {
    return (unsigned)f2bf(a) | ((unsigned)f2bf(b) << 16);
}
__device__ __forceinline__ float bf2f(short v) {
    return __uint_as_float((unsigned)(unsigned short)v << 16);
}

// async global->LDS, 16B per lane; LDS dest = uniform base + lane*16
__device__ __forceinline__ void gl_lds16(const void* g, void* l) {
    __builtin_amdgcn_global_load_lds(
        (const __attribute__((address_space(1))) unsigned*)g,
        (__attribute__((address_space(3))) unsigned*)l, 16, 0, 0);
}

// ---- prepass: Q,K fp32 -> bf16 ----
__global__ void prep_qk(const float* __restrict__ Q, const float* __restrict__ K,
                        unsigned short* __restrict__ Qb, unsigned short* __restrict__ Kb) {
    unsigned i4 = blockIdx.x * 256u + threadIdx.x;
    const float* src; unsigned short* dst;
    if (i4 < 2097152u) { src = Q; dst = Qb; }
    else { i4 -= 2097152u; src = K; dst = Kb; }
    f32x4 v = __builtin_nontemporal_load(&((const f32x4*)src)[i4]);
    u16x4 o; o[0] = f2bf(v[0]); o[1] = f2bf(v[1]); o[2] = f2bf(v[2]); o[3] = f2bf(v[3]);
    ((u16x4*)dst)[i4] = o;
}

// ---- prepass: V fp32 [bh][s][d] -> bf16 plain transpose [bh][d][s] ----
__global__ void prep_v(const float* __restrict__ V, unsigned short* __restrict__ VT) {
    __shared__ unsigned short tile[64][72];
    const int t = threadIdx.x;
    const int bh = blockIdx.x >> 5;
    const int s0 = (blockIdx.x & 31) * 64;
    const float* vb = V + ((size_t)bh * SEQ + s0) * DH;
    #pragma unroll
    for (int pp = 0; pp < 4; ++pp) {
        const int sr = pp * 16 + (t >> 4);
        const int dc = (t & 15) * 4;
        f32x4 v = __builtin_nontemporal_load((const f32x4*)(vb + sr * DH + dc));
        tile[sr][dc]     = f2bf(v[0]); tile[sr][dc + 1] = f2bf(v[1]);
        tile[sr][dc + 2] = f2bf(v[2]); tile[sr][dc + 3] = f2bf(v[3]);
    }
    __syncthreads();
    const int d = t >> 2, c = (t & 3) * 16;
    short8 w0, w1;
    #pragma unroll
    for (int j = 0; j < 8; ++j) { w0[j] = (short)tile[c + j][d]; w1[j] = (short)tile[c + 8 + j][d]; }
    unsigned short* o = VT + ((size_t)bh * DH + d) * SEQ + s0 + c;
    *(short8*)o = w0; *(short8*)(o + 8) = w1;
}

// ---- prepass: mask int32 -> bit-packed uint64 per (row, wv, lg) ----
__global__ void prep_m(const int* __restrict__ M, unsigned long long* __restrict__ M2) {
    __shared__ unsigned char mb[8][2048];
    const int t = threadIdx.x;                  // 256
    const int row0 = blockIdx.x * 8;            // of 8192 (b*SEQ+q) rows
    const i32x4* src = (const i32x4*)(M + (size_t)row0 * SEQ);
    #pragma unroll
    for (int i = 0; i < 16; ++i) {
        const int idx = i * 256 + t;            // 0..4095
        i32x4 v = __builtin_nontemporal_load(&src[idx]);
        const int r = idx >> 9, c = (idx & 511) * 4;
        mb[r][c]     = (unsigned char)(v[0] != 0);
        mb[r][c + 1] = (unsigned char)(v[1] != 0);
        mb[r][c + 2] = (unsigned char)(v[2] != 0);
        mb[r][c + 3] = (unsigned char)(v[3] != 0);
    }
    __syncthreads();
    const int r = t >> 5, w = t & 31;
    const int wv = w >> 2, lg = w & 3;
    unsigned long long acc = 0ull;
    #pragma unroll
    for (int ci = 0; ci < 16; ++ci)
        #pragma unroll
        for (int rr = 0; rr < 4; ++rr)
            acc |= (unsigned long long)(mb[r][ci * 128 + 16 * wv + 4 * lg + rr] & 1)
                   << (4 * ci + rr);
    M2[(size_t)(row0 + r) * 32 + w] = acc;
}

// ==== main (verified round-12): LDS-staged double-buffered attention ====
__global__ __launch_bounds__(NT, 4) void attn_staged(
    const unsigned short* __restrict__ Qb, const unsigned short* __restrict__ Kb,
    const unsigned short* __restrict__ VT, const unsigned long long* __restrict__ M2,
    float* __restrict__ O, float* __restrict__ W)
{
    __shared__ union {
        short stage[2][16384];
        float part[NW][QT][68];
    } u;
    __shared__ float reds[NW * 16], rowRL[QT];

    const int tid = threadIdx.x, wv = tid >> 6, ln = tid & 63;
    const int lr = ln & 15, lg = ln >> 4;
    const int bid = blockIdx.x;
    const int h = bid & 15, t2 = bid >> 4;
    const int qt = t2 & 127, b = t2 >> 7;
    const int bh = b * NH + h, q0 = qt * QT;

    const float SC = 0.18033688011112042f;       // 0.125 * log2(e)

    const unsigned short* qp = Qb + ((size_t)bh * SEQ + q0 + lr) * DH + 8 * lg;
    const short8 qf0 = *(const short8*)qp;
    const short8 qf1 = *(const short8*)(qp + 32);
    const unsigned long long mword = M2[((size_t)b * SEQ + q0 + lr) * 32 + wv * 4 + lg];

    const unsigned short* Kg = Kb + (size_t)bh * SEQ * DH;
    const unsigned short* Vg = VT + (size_t)bh * DH * SEQ;

    auto STAGE = [&](int ci, int bb) {
        const int cb = ci * CHUNK;
        #pragma unroll
        for (int jj = 0; jj < 2; ++jj) {
            const int j = 2 * wv + jj;
            const unsigned short* ks = Kg + (size_t)(cb + 8 * j + (ln >> 3)) * DH
                                          + (((ln & 7) ^ (ln >> 3)) << 3);
            gl_lds16(ks, (char*)&u.stage[bb][0] + j * 1024);
            const int d = 4 * j + (ln >> 4);
            const unsigned short* vs = Vg + (size_t)d * SEQ + cb
                                          + (((ln & 15) ^ (d & 7)) << 3);
            gl_lds16(vs, (char*)&u.stage[bb][8192] + j * 1024);
        }
    };

    STAGE(0, 0);
    __syncthreads();

    unsigned pe[2 * NCH];
    f32x4 acc[4] = {{0.f,0.f,0.f,0.f},{0.f,0.f,0.f,0.f},{0.f,0.f,0.f,0.f},{0.f,0.f,0.f,0.f}};
    float l = 0.f;

    #pragma unroll
    for (int ci = 0; ci < NCH; ++ci) {
        const int bb = ci & 1;
        if (ci + 1 < NCH) STAGE(ci + 1, bb ^ 1);

        const char* kb8 = (const char*)&u.stage[bb][0];
        const int krow = (16 * wv + lr) * 128;
        const short8 ka0 = *(const short8*)(kb8 + krow + (((lg)     ^ (lr & 7)) << 4));
        const short8 ka1 = *(const short8*)(kb8 + krow + (((4 + lg) ^ (lr & 7)) << 4));
        const char* vb8 = (const char*)&u.stage[bb][8192];
        const int vsl = ((4 * wv + lg) ^ (2 * (lr & 7))) << 3;
        short4v vv[4];
        #pragma unroll
        for (int nb = 0; nb < 4; ++nb)
            vv[nb] = *(const short4v*)(vb8 + (nb * 16 + lr) * 256 + vsl);

        f32x4 a = {0.f, 0.f, 0.f, 0.f};
        a = __builtin_amdgcn_mfma_f32_16x16x32_bf16(ka0, qf0, a, 0, 0, 0);
        a = __builtin_amdgcn_mfma_f32_16x16x32_bf16(ka1, qf1, a, 0, 0, 0);
        const unsigned nib = (unsigned)(mword >> (4 * ci)) & 0xFu;
        const float e0 = (nib & 1u) ? __builtin_amdgcn_exp2f(a[0] * SC) : 0.f;
        const float e1 = (nib & 2u) ? __builtin_amdgcn_exp2f(a[1] * SC) : 0.f;
        const float e2 = (nib & 4u) ? __builtin_amdgcn_exp2f(a[2] * SC) : 0.f;
        const float e3 = (nib & 8u) ? __builtin_amdgcn_exp2f(a[3] * SC) : 0.f;
        l += e0 + e1 + e2 + e3;
        pe[2 * ci]     = pk2(e0, e1);
        pe[2 * ci + 1] = pk2(e2, e3);
        union { uint2 w; short4v s; } pu;
        pu.w.x = pe[2 * ci]; pu.w.y = pe[2 * ci + 1];
        #pragma unroll
        for (int nb = 0; nb < 4; ++nb)
            acc[nb] = __builtin_amdgcn_mfma_f32_16x16x16bf16_1k(pu.s, vv[nb], acc[nb], 0, 0, 0);

        __syncthreads();
    }

    l += __shfl_xor(l, 16);
    l += __shfl_xor(l, 32);
    if (ln < 16) reds[wv * 16 + ln] = l;
    __syncthreads();

    float Lq = 0.f;
    #pragma unroll
    for (int w = 0; w < NW; ++w) Lq += reds[w * 16 + lr];
    const float rl = Lq > 0.f ? 1.f / Lq : 0.f;
    if (wv == 0 && ln < 16) rowRL[ln] = rl;

    {
        char* wb = (char*)&u.stage[0][0];
        const int rowbase = lr * 4096;
        const int sw = (lr & 7) << 5;
        #pragma unroll
        for (int ci = 0; ci < NCH; ++ci) {
            uint2 pk; pk.x = pe[2 * ci]; pk.y = pe[2 * ci + 1];
            const int cbyte = (ci * 256 + 32 * wv + 8 * lg) ^ sw;
            *(uint2*)(wb + rowbase + cbyte) = pk;
        }
    }
    __syncthreads();

    {
        const char* wb = (const char*)&u.stage[0][0];
        float* Wb = W + (size_t)bh * SEQ * SEQ + (size_t)q0 * SEQ;
        #pragma unroll
        for (int rr = 0; rr < 2; ++rr) {
            const int row = 2 * wv + rr;
            const char* rbase = wb + row * 4096;
            const int sw = (row & 7) << 5;
            const float wrl = rowRL[row];
            float* Wr = Wb + (size_t)row * SEQ;
            #pragma unroll
            for (int it = 0; it < 4; ++it) {
                short8 v = *(const short8*)(rbase + ((it * 1024 + ln * 16) ^ sw));
                f32x4 o0, o1;
                o0[0] = bf2f(v[0]) * wrl; o0[1] = bf2f(v[1]) * wrl;
                o0[2] = bf2f(v[2]) * wrl; o0[3] = bf2f(v[3]) * wrl;
                o1[0] = bf2f(v[4]) * wrl; o1[1] = bf2f(v[5]) * wrl;
                o1[2] = bf2f(v[6]) * wrl; o1[3] = bf2f(v[7]) * wrl;
                __builtin_nontemporal_store(o0, (f32x4*)(Wr + it * 512 + ln * 8));
                __builtin_nontemporal_store(o1, (f32x4*)(Wr + it * 512 + ln * 8 + 4));
            }
        }
    }
    __syncthreads();

    #pragma unroll
    for (int nb = 0; nb < 4; ++nb)
        #pragma unroll
        for (int r = 0; r < 4; ++r)
            u.part[wv][4 * lg + r][nb * 16 + lr] = acc[nb][r];
    __syncthreads();
    float* Ob = O + ((size_t)bh * SEQ + q0) * DH;
    for (int e = tid; e < QT * DH; e += NT) {
        const int q = e >> 6, d = e & 63;
        float s = 0.f;
        #pragma unroll
        for (int w = 0; w < NW; ++w) s += u.part[w][q][d];
        __builtin_nontemporal_store(s * rowRL[q], &Ob[e]);
    }
}

// ==== ABLATION 1: staging loop only (x3 reps) — pure L2->LDS throughput ====
__global__ __launch_bounds__(NT, 4) void abl_stage(
    const unsigned short* __restrict__ Kb, const unsigned short* __restrict__ VT,
    float* __restrict__ out)
{
    __shared__ short stage[2][16384];
    const int tid = threadIdx.x, wv = tid >> 6, ln = tid & 63;
    const int lr = ln & 15, lg = ln >> 4;
    const int bid = blockIdx.x;
    const int h = bid & 15, t2 = bid >> 4, b = t2 >> 7;
    const int bh = b * NH + h;
    const unsigned short* Kg = Kb + (size_t)bh * SEQ * DH;
    const unsigned short* Vg = VT + (size_t)bh * DH * SEQ;

    auto STAGE = [&](int ci, int bb) {
        const int cb = ci * CHUNK;
        #pragma unroll
        for (int jj = 0; jj < 2; ++jj) {
            const int j = 2 * wv + jj;
            const unsigned short* ks = Kg + (size_t)(cb + 8 * j + (ln >> 3)) * DH
                                          + (((ln & 7) ^ (ln >> 3)) << 3);
            gl_lds16(ks, (char*)&stage[bb][0] + j * 1024);
            const int d = 4 * j + (ln >> 4);
            const unsigned short* vs = Vg + (size_t)d * SEQ + cb
                                          + (((ln & 15) ^ (d & 7)) << 3);
            gl_lds16(vs, (char*)&stage[bb][8192] + j * 1024);
        }
    };

    #pragma unroll 1
    for (int rep = 0; rep < 3; ++rep) {
        STAGE(0, 0);
        __syncthreads();
        #pragma unroll 1
        for (int ci = 0; ci < NCH; ++ci) {
            const int bb = ci & 1;
            if (ci + 1 < NCH) STAGE(ci + 1, bb ^ 1);
            const char* kb8 = (const char*)&stage[bb][0];
            const int krow = (16 * wv + lr) * 128;
            const short8 ka0 = *(const short8*)(kb8 + krow + (((lg)     ^ (lr & 7)) << 4));
            const short8 ka1 = *(const short8*)(kb8 + krow + (((4 + lg) ^ (lr & 7)) << 4));
            const char* vb8 = (const char*)&stage[bb][8192];
            const int vsl = ((4 * wv + lg) ^ (2 * (lr & 7))) << 3;
            short4v v0 = *(const short4v*)(vb8 + (0 * 16 + lr) * 256 + vsl);
            short4v v1 = *(const short4v*)(vb8 + (1 * 16 + lr) * 256 + vsl);
            short4v v2 = *(const short4v*)(vb8 + (2 * 16 + lr) * 256 + vsl);
            short4v v3 = *(const short4v*)(vb8 + (3 * 16 + lr) * 256 + vsl);
            asm volatile("" :: "v"(ka0), "v"(ka1), "v"(v0), "v"(v1), "v"(v2), "v"(v3));
            __syncthreads();
        }
    }
    if (tid == 0) out[bid & 4095] = 1.f;
}

// ==== ABLATION 2: full kernel, W/O stores into 8MB L2 window (x3 reps) ====
__global__ __launch_bounds__(NT, 4) void abl_nowrite(
    const unsigned short* __restrict__ Qb, const unsigned short* __restrict__ Kb,
    const unsigned short* __restrict__ VT, const unsigned long long* __restrict__ M2,
    float* __restrict__ win)
{
    __shared__ union {
        short stage[2][16384];
        float part[NW][QT][68];
    } u;
    __shared__ float reds[NW * 16], rowRL[QT];

    const int tid = threadIdx.x, wv = tid >> 6, ln = tid & 63;
    const int lr = ln & 15, lg = ln >> 4;
    const int bid = blockIdx.x;
    const int h = bid & 15, t2 = bid >> 4;
    const int qt = t2 & 127, b = t2 >> 7;
    const int bh = b * NH + h, q0 = qt * QT;

    const float SC = 0.18033688011112042f;

    const unsigned short* qp = Qb + ((size_t)bh * SEQ + q0 + lr) * DH + 8 * lg;
    const short8 qf0 = *(const short8*)qp;
    const short8 qf1 = *(const short8*)(qp + 32);
    const unsigned long long mword = M2[((size_t)b * SEQ + q0 + lr) * 32 + wv * 4 + lg];

    const unsigned short* Kg = Kb + (size_t)bh * SEQ * DH;
    const unsigned short* Vg = VT + (size_t)bh * DH * SEQ;

    auto STAGE = [&](int ci, int bb) {
        const int cb = ci * CHUNK;
        #pragma unroll
        for (int jj = 0; jj < 2; ++jj) {
            const int j = 2 * wv + jj;
            const unsigned short* ks = Kg + (size_t)(cb + 8 * j + (ln >> 3)) * DH
                                          + (((ln & 7) ^ (ln >> 3)) << 3);
            gl_lds16(ks, (char*)&u.stage[bb][0] + j * 1024);
            const int d = 4 * j + (ln >> 4);
            const unsigned short* vs = Vg + (size_t)d * SEQ + cb
                                          + (((ln & 15) ^ (d & 7)) << 3);
            gl_lds16(vs, (char*)&u.stage[bb][8192] + j * 1024);
        }
    };

    #pragma unroll 1
    for (int rep = 0; rep < 3; ++rep) {
        STAGE(0, 0);
        __syncthreads();

        unsigned pe[2 * NCH];
        f32x4 acc[4] = {{0.f,0.f,0.f,0.f},{0.f,0.f,0.f,0.f},{0.f,0.f,0.f,0.f},{0.f,0.f,0.f,0.f}};
        float l = 0.f;

        #pragma unroll 1
        for (int ci = 0; ci < NCH; ++ci) {
            const int bb = ci & 1;
            if (ci + 1 < NCH) STAGE(ci + 1, bb ^ 1);

            const char* kb8 = (const char*)&u.stage[bb][0];
            const int krow = (16 * wv + lr) * 128;
            const short8 ka0 = *(const short8*)(kb8 + krow + (((lg)     ^ (lr & 7)) << 4));
            const short8 ka1 = *(const short8*)(kb8 + krow + (((4 + lg) ^ (lr & 7)) << 4));
            const char* vb8 = (const char*)&u.stage[bb][8192];
            const int vsl = ((4 * wv + lg) ^ (2 * (lr & 7))) << 3;
            short4v vv[4];
            #pragma unroll
            for (int nb = 0; nb < 4; ++nb)
                vv[nb] = *(const short4v*)(vb8 + (nb * 16 + lr) * 256 + vsl);

            f32x4 a = {0.f, 0.f, 0.f, 0.f};
            a = __builtin_amdgcn_mfma_f32_16x16x32_bf16(ka0, qf0, a, 0, 0, 0);
            a = __builtin_amdgcn_mfma_f32_16x16x32_bf16(ka1, qf1, a, 0, 0, 0);
            const unsigned nib = (unsigned)(mword >> (4 * ci)) & 0xFu;
            const float e0 = (nib & 1u) ? __builtin_amdgcn_exp2f(a[0] * SC) : 0.f;
            const float e1 = (nib & 2u) ? __builtin_amdgcn_exp2f(a[1] * SC) : 0.f;
            const float e2 = (nib & 4u) ? __builtin_amdgcn_exp2f(a[2] * SC) : 0.f;
            const float e3 = (nib & 8u) ? __builtin_amdgcn_exp2f(a[3] * SC) : 0.f;
            l += e0 + e1 + e2 + e3;
            pe[2 * ci]     = pk2(e0, e1);
            pe[2 * ci + 1] = pk2(e2, e3);
            union { uint2 w; short4v s; } pu;
            pu.w.x = pe[2 * ci]; pu.w.y = pe[2 * ci + 1];
            #pragma unroll
            for (int nb = 0; nb < 4; ++nb)
                acc[nb] = __builtin_amdgcn_mfma_f32_16x16x16bf16_1k(pu.s, vv[nb], acc[nb], 0, 0, 0);

            __syncthreads();
        }

        l += __shfl_xor(l, 16);
        l += __shfl_xor(l, 32);
        if (ln < 16) reds[wv * 16 + ln] = l;
        __syncthreads();

        float Lq = 0.f;
        #pragma unroll
        for (int w = 0; w < NW; ++w) Lq += reds[w * 16 + lr];
        const float rl = Lq > 0.f ? 1.f / Lq : 0.f;
        if (wv == 0 && ln < 16) rowRL[ln] = rl;

        {
            char* wb = (char*)&u.stage[0][0];
            const int rowbase = lr * 4096;
            const int sw = (lr & 7) << 5;
            #pragma unroll
            for (int ci = 0; ci < NCH; ++ci) {
                uint2 pk; pk.x = pe[2 * ci]; pk.y = pe[2 * ci + 1];
                const int cbyte = (ci * 256 + 32 * wv + 8 * lg) ^ sw;
                *(uint2*)(wb + rowbase + cbyte) = pk;
            }
        }
        __syncthreads();

        // W-b: same instruction stream, but into an L2-resident 8MB window
        {
            const char* wb = (const char*)&u.stage[0][0];
            const size_t wbase = ((size_t)bh * SEQ * SEQ + (size_t)q0 * SEQ) & 2097151u;
            float* Wb = win + wbase;
            #pragma unroll
            for (int rr = 0; rr < 2; ++rr) {
                const int row = 2 * wv + rr;
                const char* rbase = wb + row * 4096;
                const int sw = (row & 7) << 5;
                const float wrl = rowRL[row];
                float* Wr = Wb + ((size_t)row * SEQ & 2097151u);
                #pragma unroll
                for (int it = 0; it < 4; ++it) {
                    short8 v = *(const short8*)(rbase + ((it * 1024 + ln * 16) ^ sw));
                    f32x4 o0, o1;
                    o0[0] = bf2f(v[0]) * wrl; o0[1] = bf2f(v[1]) * wrl;
                    o0[2] = bf2f(v[2]) * wrl; o0[3] = bf2f(v[3]) * wrl;
                    o1[0] = bf2f(v[4]) * wrl; o1[1] = bf2f(v[5]) * wrl;
                    o1[2] = bf2f(v[6]) * wrl; o1[3] = bf2f(v[7]) * wrl;
                    *(f32x4*)(Wr + it * 512 + ln * 8) = o0;
                    *(f32x4*)(Wr + it * 512 + ln * 8 + 4) = o1;
                }
            }
        }
        __syncthreads();

        #pragma unroll
        for (int nb = 0; nb < 4; ++nb)
            #pragma unroll
            for (int r = 0; r < 4; ++r)
                u.part[wv][4 * lg + r][nb * 16 + lr] = acc[nb][r];
        __syncthreads();
        float* Ob = win + (((size_t)bh * SEQ + q0) * DH & 2097151u);
        for (int e = tid; e < QT * DH; e += NT) {
            const int q = e >> 6, d = e & 63;
            float s = 0.f;
            #pragma unroll
            for (int w = 0; w < NW; ++w) s += u.part[w][q][d];
            Ob[e] = s * rowRL[q];
        }
        __syncthreads();
    }
}

// ---- compact correctness-only fallback ----
__global__ void attn_naive(const float* __restrict__ Q, const float* __restrict__ K,
                           const float* __restrict__ V, const int* __restrict__ M,
                           float* __restrict__ O, float* __restrict__ W) {
    __shared__ float sc[SEQ];
    __shared__ float red[256];
    const int bh = blockIdx.x >> 11, q = blockIdx.x & 2047, b = bh >> 4;
    const int t = threadIdx.x;
    const float* Qr = Q + ((size_t)bh * SEQ + q) * DH;
    const int* Mr = M + (size_t)b * SEQ * SEQ + (size_t)q * SEQ;
    for (int k = t; k < SEQ; k += 256) {
        const float* Kr = K + ((size_t)bh * SEQ + k) * DH;
        float s = 0.f;
        for (int d = 0; d < DH; ++d) s += Qr[d] * Kr[d];
        sc[k] = Mr[k] ? s * 0.125f : -INFINITY;
    }
    __syncthreads();
    float m = -INFINITY;
    for (int k = t; k < SEQ; k += 256) m = fmaxf(m, sc[k]);
    red[t] = m; __syncthreads();
    for (int o = 128; o; o >>= 1) { if (t < o) red[t] = fmaxf(red[t], red[t + o]); __syncthreads(); }
    m = red[0]; __syncthreads();
    float ls = 0.f;
    for (int k = t; k < SEQ; k += 256) { float e = __expf(sc[k] - m); sc[k] = e; ls += e; }
    red[t] = ls; __syncthreads();
    for (int o = 128; o; o >>= 1) { if (t < o) red[t] += red[t + o]; __syncthreads(); }
    const float rl = 1.f / red[0];
    float* Wr = W + (size_t)bh * SEQ * SEQ + (size_t)q * SEQ;
    for (int k = t; k < SEQ; k += 256) Wr[k] = sc[k] * rl;
    if (t < DH) {
        float o = 0.f;
        for (int k = 0; k < SEQ; ++k) o += sc[k] * V[((size_t)bh * SEQ + k) * DH + t];
        O[((size_t)bh * SEQ + q) * DH + t] = o * rl;
    }
}

extern "C" void kernel_launch(void* const* d_in, const int* in_sizes, int n_in,
                              void* d_out, int out_size, void* d_ws, size_t ws_size,
                              hipStream_t stream) {
    const float* Q = (const float*)d_in[0];
    const float* K = (const float*)d_in[1];
    const float* V = (const float*)d_in[2];
    const int*   M = (const int*)d_in[3];
    float* O = (float*)d_out;
    float* W = O + (size_t)NBH * SEQ * DH;

    const bool pre = ws_size >= (size_t)67108864;   // 64 MiB scratch layout
    unsigned short* Qb = (unsigned short*)d_ws;
    unsigned short* Kb = Qb + (size_t)8388608;
    unsigned short* VT = Qb + (size_t)2 * 8388608;
    unsigned long long* M2 = (unsigned long long*)(Qb + (size_t)3 * 8388608);  // @48MB, 2MB
    float* WIN = (float*)((char*)d_ws + (size_t)56 * 1048576);                 // @56MB, 8MB

    if (pre) {
        prep_qk<<<16384, 256, 0, stream>>>(Q, K, Qb, Kb);
        prep_v<<<2048, 256, 0, stream>>>(V, VT);
        prep_m<<<1024, 256, 0, stream>>>(M, M2);
        attn_staged<<<8192, NT, 0, stream>>>(Qb, Kb, VT, M2, O, W);
        // diagnostic ablations (write only to d_ws; x3 internal reps each)
        abl_stage<<<8192, NT, 0, stream>>>(Kb, VT, WIN);
        abl_nowrite<<<8192, NT, 0, stream>>>(Qb, Kb, VT, M2, WIN);
    } else {
        attn_naive<<<NBH * SEQ, 256, 0, stream>>>(Q, K, V, M, O, W);
    }
}

// Round 16
// 413.096 us; speedup vs baseline: 5.4303x; 5.4303x over previous
//
#include <hip/hip_runtime.h>
#include <hip/hip_bf16.h>

#define SEQ   2048
#define DH    64
#define NBH   64          // B*H
#define NH    16
#define QT    16          // q-rows per block
#define NW    8           // waves per block
#define NT    (NW * 64)
#define CHUNK 128         // k-cols per chunk
#define NCH   (SEQ / CHUNK)

typedef __attribute__((ext_vector_type(8))) short short8;
typedef __attribute__((ext_vector_type(4))) short short4v;
typedef __attribute__((ext_vector_type(4))) float f32x4;
typedef __attribute__((ext_vector_type(4))) int   i32x4;
typedef __attribute__((ext_vector_type(4))) unsigned short u16x4;

__device__ __forceinline__ unsigned short f2bf(float x) {
    union { float f; unsigned u; } c; c.f = x;
    return (unsigned short)((c.u + 0x7fffu + ((c.u >> 16) & 1u)) >> 16);
}
__device__ __forceinline__ unsigned pk2(float a, float b) {
    return (unsigned)f2bf(a) | ((unsigned)f2bf(b) << 16);
}
__device__ __forceinline__ float bf2f(short v) {
    return __uint_as_float((unsigned)(unsigned short)v << 16);
}

// async global->LDS, 16B per lane; LDS dest = uniform base + lane*16
__device__ __forceinline__ void gl_lds16(const void* g, void* l) {
    __builtin_amdgcn_global_load_lds(
        (const __attribute__((address_space(1))) unsigned*)g,
        (__attribute__((address_space(3))) unsigned*)l, 16, 0, 0);
}

// ---- prepass: Q,K fp32 -> bf16 ----
__global__ void prep_qk(const float* __restrict__ Q, const float* __restrict__ K,
                        unsigned short* __restrict__ Qb, unsigned short* __restrict__ Kb) {
    unsigned i4 = blockIdx.x * 256u + threadIdx.x;
    const float* src; unsigned short* dst;
    if (i4 < 2097152u) { src = Q; dst = Qb; }
    else { i4 -= 2097152u; src = K; dst = Kb; }
    f32x4 v = __builtin_nontemporal_load(&((const f32x4*)src)[i4]);
    u16x4 o; o[0] = f2bf(v[0]); o[1] = f2bf(v[1]); o[2] = f2bf(v[2]); o[3] = f2bf(v[3]);
    ((u16x4*)dst)[i4] = o;
}

// ---- prepass: V fp32 [bh][s][d] -> bf16 chunk-blocked transpose ----
// layout: [bh][ci=s>>7][wslice=(s>>4)&7][d][s&15]  (each wave-chunk slice = 2KB contig)
__global__ void prep_v(const float* __restrict__ V, unsigned short* __restrict__ VT) {
    __shared__ unsigned short tile[64][72];
    const int t = threadIdx.x;
    const int bh = blockIdx.x >> 5;
    const int s0 = (blockIdx.x & 31) * 64;
    const float* vb = V + ((size_t)bh * SEQ + s0) * DH;
    #pragma unroll
    for (int pp = 0; pp < 4; ++pp) {
        const int sr = pp * 16 + (t >> 4);
        const int dc = (t & 15) * 4;
        f32x4 v = __builtin_nontemporal_load((const f32x4*)(vb + sr * DH + dc));
        tile[sr][dc]     = f2bf(v[0]); tile[sr][dc + 1] = f2bf(v[1]);
        tile[sr][dc + 2] = f2bf(v[2]); tile[sr][dc + 3] = f2bf(v[3]);
    }
    __syncthreads();
    const int d = t >> 2, c = (t & 3) * 16;
    short8 w0, w1;
    #pragma unroll
    for (int j = 0; j < 8; ++j) { w0[j] = (short)tile[c + j][d]; w1[j] = (short)tile[c + 8 + j][d]; }
    const int s = s0 + c;
    unsigned short* o = VT + (size_t)bh * (SEQ * DH)
                        + (size_t)(s >> 7) * 8192 + (size_t)((s >> 4) & 7) * 1024 + d * 16;
    *(short8*)o = w0; *(short8*)(o + 8) = w1;
}

// ---- prepass: mask int32 -> bit-packed uint64 per (row, wv, lg) ----
__global__ void prep_m(const int* __restrict__ M, unsigned long long* __restrict__ M2) {
    __shared__ unsigned char mb[8][2048];
    const int t = threadIdx.x;                  // 256
    const int row0 = blockIdx.x * 8;            // of 8192 (b*SEQ+q) rows
    const i32x4* src = (const i32x4*)(M + (size_t)row0 * SEQ);
    #pragma unroll
    for (int i = 0; i < 16; ++i) {
        const int idx = i * 256 + t;            // 0..4095
        i32x4 v = __builtin_nontemporal_load(&src[idx]);
        const int r = idx >> 9, c = (idx & 511) * 4;
        mb[r][c]     = (unsigned char)(v[0] != 0);
        mb[r][c + 1] = (unsigned char)(v[1] != 0);
        mb[r][c + 2] = (unsigned char)(v[2] != 0);
        mb[r][c + 3] = (unsigned char)(v[3] != 0);
    }
    __syncthreads();
    const int r = t >> 5, w = t & 31;
    const int wv = w >> 2, lg = w & 3;
    unsigned long long acc = 0ull;
    #pragma unroll
    for (int ci = 0; ci < 16; ++ci)
        #pragma unroll
        for (int rr = 0; rr < 4; ++rr)
            acc |= (unsigned long long)(mb[r][ci * 128 + 16 * wv + 4 * lg + rr] & 1)
                   << (4 * ci + rr);
    M2[(size_t)(row0 + r) * 32 + w] = acc;
}

// ==== main: wave-private staged, barrier-free K-loop (per-wave counted vmcnt) ====
__global__ __launch_bounds__(NT, 4) void attn_staged(
    const unsigned short* __restrict__ Qb, const unsigned short* __restrict__ Kb,
    const unsigned short* __restrict__ VT, const unsigned long long* __restrict__ M2,
    float* __restrict__ O, float* __restrict__ W)
{
    __shared__ union {
        char  sbuf[NW][2][4096];                 // per-wave: [K 2KB][V 2KB] x dbuf
        char  wmat[16][4096];                    // W staging area (64KB)
        float part[NW][QT][68];
    } u;
    __shared__ float reds[NW * 16], rowRL[QT];

    const int tid = threadIdx.x, wv = tid >> 6, ln = tid & 63;
    const int lr = ln & 15, lg = ln >> 4;
    const int bid = blockIdx.x;                  // h fastest: head->XCD pinning
    const int h = bid & 15, t2 = bid >> 4;
    const int qt = t2 & 127, b = t2 >> 7;
    const int bh = b * NH + h, q0 = qt * QT;

    const float SC = 0.18033688011112042f;       // 0.125 * log2(e)

    // prologue loads: Q frags + packed mask word; drain so vmcnt counts only STAGEs
    const unsigned short* qp = Qb + ((size_t)bh * SEQ + q0 + lr) * DH + 8 * lg;
    const short8 qf0 = *(const short8*)qp;
    const short8 qf1 = *(const short8*)(qp + 32);
    const unsigned long long mword = M2[((size_t)b * SEQ + q0 + lr) * 32 + wv * 4 + lg];
    asm volatile("s_waitcnt vmcnt(0)" ::: "memory");
    __builtin_amdgcn_sched_barrier(0);

    const unsigned short* Kg = Kb + (size_t)bh * SEQ * DH;
    const unsigned short* Vg = VT + (size_t)bh * (SEQ * DH);

    // stage this wave's private K slice (16 rows) + V slice (2KB blocked) for chunk ci
    auto STAGE = [&](int ci, int bb) {
        const int cb = ci * CHUNK + 16 * wv;
        #pragma unroll
        for (int tt = 0; tt < 2; ++tt) {
            const unsigned short* ks = Kg + (size_t)(cb + 8 * tt + (ln >> 3)) * DH
                                          + (((ln & 7) ^ (ln >> 3)) << 3);
            gl_lds16(ks, &u.sbuf[wv][bb][tt * 1024]);
        }
        const unsigned short* vsb = Vg + ci * 8192 + wv * 1024;
        #pragma unroll
        for (int hh = 0; hh < 2; ++hh)
            gl_lds16(vsb + hh * 512 + ln * 8, &u.sbuf[wv][bb][2048 + hh * 1024]);
    };

    STAGE(0, 0);
    STAGE(1, 1);                                 // 8 loads outstanding

    unsigned pe[2 * NCH];
    f32x4 acc[4] = {{0.f,0.f,0.f,0.f},{0.f,0.f,0.f,0.f},{0.f,0.f,0.f,0.f},{0.f,0.f,0.f,0.f}};
    float l = 0.f;

    #pragma unroll
    for (int ci = 0; ci < NCH; ++ci) {
        const int bb = ci & 1;
        // wait: chunk ci resident (its 4 loads done); next chunk's 4 stay in flight
        if (ci + 1 < NCH) asm volatile("s_waitcnt vmcnt(4)" ::: "memory");
        else              asm volatile("s_waitcnt vmcnt(0)" ::: "memory");
        __builtin_amdgcn_sched_barrier(0);

        // K frags from private slice (swizzled, 2-way free)
        const char* kb8 = (const char*)&u.sbuf[wv][bb][0];
        const int kro = (lr >> 3) * 1024 + (lr & 7) * 128;
        const short8 ka0 = *(const short8*)(kb8 + kro + (((lg)     ^ (lr & 7)) << 4));
        const short8 ka1 = *(const short8*)(kb8 + kro + (((4 + lg) ^ (lr & 7)) << 4));
        // V frags from private blocked slice [d][16k]
        const char* vb8 = (const char*)&u.sbuf[wv][bb][2048];
        short4v vv[4];
        #pragma unroll
        for (int nb = 0; nb < 4; ++nb)
            vv[nb] = *(const short4v*)(vb8 + (nb * 16 + lr) * 32 + lg * 8);

        f32x4 a = {0.f, 0.f, 0.f, 0.f};
        a = __builtin_amdgcn_mfma_f32_16x16x32_bf16(ka0, qf0, a, 0, 0, 0);
        a = __builtin_amdgcn_mfma_f32_16x16x32_bf16(ka1, qf1, a, 0, 0, 0);
        const unsigned nib = (unsigned)(mword >> (4 * ci)) & 0xFu;
        const float e0 = (nib & 1u) ? __builtin_amdgcn_exp2f(a[0] * SC) : 0.f;
        const float e1 = (nib & 2u) ? __builtin_amdgcn_exp2f(a[1] * SC) : 0.f;
        const float e2 = (nib & 4u) ? __builtin_amdgcn_exp2f(a[2] * SC) : 0.f;
        const float e3 = (nib & 8u) ? __builtin_amdgcn_exp2f(a[3] * SC) : 0.f;
        l += e0 + e1 + e2 + e3;
        pe[2 * ci]     = pk2(e0, e1);
        pe[2 * ci + 1] = pk2(e2, e3);
        union { uint2 w; short4v s; } pu;
        pu.w.x = pe[2 * ci]; pu.w.y = pe[2 * ci + 1];
        #pragma unroll
        for (int nb = 0; nb < 4; ++nb)
            acc[nb] = __builtin_amdgcn_mfma_f32_16x16x16bf16_1k(pu.s, vv[nb], acc[nb], 0, 0, 0);

        // prefetch chunk ci+2 into the buffer just consumed (own reads retired first)
        if (ci + 2 < NCH) {
            asm volatile("s_waitcnt lgkmcnt(0)" ::: "memory");
            __builtin_amdgcn_sched_barrier(0);
            STAGE(ci + 2, bb);
        }
    }

    // combine lane-groups (same q=lr) then waves
    l += __shfl_xor(l, 16);
    l += __shfl_xor(l, 32);
    if (ln < 16) reds[wv * 16 + ln] = l;
    __syncthreads();                             // also: all waves' K-loop done

    float Lq = 0.f;
    #pragma unroll
    for (int w = 0; w < NW; ++w) Lq += reds[w * 16 + lr];
    const float rl = Lq > 0.f ? 1.f / Lq : 0.f;
    if (wv == 0 && ln < 16) rowRL[ln] = rl;

    // ---- phase W-a: raw bf16 e-pairs into wmat (XOR-swizzled rows) ----
    {
        char* wb = &u.wmat[0][0];
        const int rowbase = lr * 4096;
        const int sw = (lr & 7) << 5;
        #pragma unroll
        for (int ci = 0; ci < NCH; ++ci) {
            uint2 pk; pk.x = pe[2 * ci]; pk.y = pe[2 * ci + 1];
            const int cbyte = (ci * 256 + 32 * wv + 8 * lg) ^ sw;
            *(uint2*)(wb + rowbase + cbyte) = pk;
        }
    }
    __syncthreads();

    // ---- phase W-b: coalesced W store (wave owns 2 rows; 1KB contiguous NT) ----
    {
        const char* wb = &u.wmat[0][0];
        float* Wb = W + (size_t)bh * SEQ * SEQ + (size_t)q0 * SEQ;
        #pragma unroll
        for (int rr = 0; rr < 2; ++rr) {
            const int row = 2 * wv + rr;
            const char* rbase = wb + row * 4096;
            const int sw = (row & 7) << 5;
            const float wrl = rowRL[row];
            float* Wr = Wb + (size_t)row * SEQ;
            #pragma unroll
            for (int it = 0; it < 4; ++it) {
                short8 v = *(const short8*)(rbase + ((it * 1024 + ln * 16) ^ sw));
                f32x4 o0, o1;
                o0[0] = bf2f(v[0]) * wrl; o0[1] = bf2f(v[1]) * wrl;
                o0[2] = bf2f(v[2]) * wrl; o0[3] = bf2f(v[3]) * wrl;
                o1[0] = bf2f(v[4]) * wrl; o1[1] = bf2f(v[5]) * wrl;
                o1[2] = bf2f(v[6]) * wrl; o1[3] = bf2f(v[7]) * wrl;
                __builtin_nontemporal_store(o0, (f32x4*)(Wr + it * 512 + ln * 8));
                __builtin_nontemporal_store(o1, (f32x4*)(Wr + it * 512 + ln * 8 + 4));
            }
        }
    }
    __syncthreads();

    // ---- phase O: cross-wave reduction ----
    #pragma unroll
    for (int nb = 0; nb < 4; ++nb)
        #pragma unroll
        for (int r = 0; r < 4; ++r)
            u.part[wv][4 * lg + r][nb * 16 + lr] = acc[nb][r];
    __syncthreads();
    float* Ob = O + ((size_t)bh * SEQ + q0) * DH;
    for (int e = tid; e < QT * DH; e += NT) {
        const int q = e >> 6, d = e & 63;
        float s = 0.f;
        #pragma unroll
        for (int w = 0; w < NW; ++w) s += u.part[w][q][d];
        __builtin_nontemporal_store(s * rowRL[q], &Ob[e]);
    }
}

// ---- compact correctness-only fallback (ws too small; never used in practice) ----
__global__ void attn_naive(const float* __restrict__ Q, const float* __restrict__ K,
                           const float* __restrict__ V, const int* __restrict__ M,
                           float* __restrict__ O, float* __restrict__ W) {
    __shared__ float sc[SEQ];
    __shared__ float red[256];
    const int bh = blockIdx.x >> 11, q = blockIdx.x & 2047, b = bh >> 4;
    const int t = threadIdx.x;
    const float* Qr = Q + ((size_t)bh * SEQ + q) * DH;
    const int* Mr = M + (size_t)b * SEQ * SEQ + (size_t)q * SEQ;
    for (int k = t; k < SEQ; k += 256) {
        const float* Kr = K + ((size_t)bh * SEQ + k) * DH;
        float s = 0.f;
        for (int d = 0; d < DH; ++d) s += Qr[d] * Kr[d];
        sc[k] = Mr[k] ? s * 0.125f : -INFINITY;
    }
    __syncthreads();
    float m = -INFINITY;
    for (int k = t; k < SEQ; k += 256) m = fmaxf(m, sc[k]);
    red[t] = m; __syncthreads();
    for (int o = 128; o; o >>= 1) { if (t < o) red[t] = fmaxf(red[t], red[t + o]); __syncthreads(); }
    m = red[0]; __syncthreads();
    float ls = 0.f;
    for (int k = t; k < SEQ; k += 256) { float e = __expf(sc[k] - m); sc[k] = e; ls += e; }
    red[t] = ls; __syncthreads();
    for (int o = 128; o; o >>= 1) { if (t < o) red[t] += red[t + o]; __syncthreads(); }
    const float rl = 1.f / red[0];
    float* Wr = W + (size_t)bh * SEQ * SEQ + (size_t)q * SEQ;
    for (int k = t; k < SEQ; k += 256) Wr[k] = sc[k] * rl;
    if (t < DH) {
        float o = 0.f;
        for (int k = 0; k < SEQ; ++k) o += sc[k] * V[((size_t)bh * SEQ + k) * DH + t];
        O[((size_t)bh * SEQ + q) * DH + t] = o * rl;
    }
}

extern "C" void kernel_launch(void* const* d_in, const int* in_sizes, int n_in,
                              void* d_out, int out_size, void* d_ws, size_t ws_size,
                              hipStream_t stream) {
    const float* Q = (const float*)d_in[0];
    const float* K = (const float*)d_in[1];
    const float* V = (const float*)d_in[2];
    const int*   M = (const int*)d_in[3];
    float* O = (float*)d_out;
    float* W = O + (size_t)NBH * SEQ * DH;

    const bool pre = ws_size >= (size_t)67108864;   // 64 MiB scratch layout
    unsigned short* Qb = (unsigned short*)d_ws;
    unsigned short* Kb = Qb + (size_t)8388608;
    unsigned short* VT = Qb + (size_t)2 * 8388608;
    unsigned long long* M2 = (unsigned long long*)(Qb + (size_t)3 * 8388608);

    if (pre) {
        prep_qk<<<16384, 256, 0, stream>>>(Q, K, Qb, Kb);
        prep_v<<<2048, 256, 0, stream>>>(V, VT);
        prep_m<<<1024, 256, 0, stream>>>(M, M2);
        attn_staged<<<8192, NT, 0, stream>>>(Qb, Kb, VT, M2, O, W);
    } else {
        attn_naive<<<NBH * SEQ, 256, 0, stream>>>(Q, K, V, M, O, W);
    }
}